// Round 8
// baseline (5502.762 us; speedup 1.0000x reference)
//
#include <hip/hip_runtime.h>
#include <hip/hip_bf16.h>

// B=64, S=512, T=64, E=H=512, V=128, G=4H=2048, Kgates=512(ctx)+512(h)+128(tgt)=1152
// R9: occupancy doubling. R6 (best, 2690us) is MLP-starved: 2 waves/SIMD stream
// K+V at 1 TB/s. Split gate K-dim across 2 blocks -> wpk[72] fits 128-VGPR cap
// -> __launch_bounds__(512,4) = 2 blocks/CU, 4 waves/SIMD, 512 blocks.
// Attention: 8 siblings/batch (s-chunk 64, single-wave softmax, 8-way combine).
// Gates: 64 blocks/XCD = 32 n-slices x 2 k-halves; cell sums 2 Gx layers.
// R8 lesson: NO prefetch register arrays, NO nt-loads (they forced scratch spill).

#define DI __device__ __forceinline__
typedef __hip_bfloat16 bf16;
typedef __hip_bfloat162 bf162;

DI float2 bf2f2(unsigned int u) {
  bf162 b = *reinterpret_cast<const bf162*>(&u);
  return __bfloat1622float2(b);
}
DI float sigm(float x) { return 1.f / (1.f + expf(-x)); }
DI void ast(float* p, float v) {
  __hip_atomic_store(p, v, __ATOMIC_RELAXED, __HIP_MEMORY_SCOPE_AGENT);
}
DI float ald(const float* p) {
  return __hip_atomic_load(p, __ATOMIC_RELAXED, __HIP_MEMORY_SCOPE_AGENT);
}
DI unsigned uld(const unsigned* p) {
  return __hip_atomic_load(p, __ATOMIC_RELAXED, __HIP_MEMORY_SCOPE_AGENT);
}

// ---------------------------------------------------------------------------
// Generic 64x64-tile fp32 GEMM (precompute only, unchanged)
// ---------------------------------------------------------------------------
template<bool BT, bool OBF, bool CT>
__launch_bounds__(256)
__global__ void gemm64(const float* __restrict__ A, const float* __restrict__ Bm,
                       void* __restrict__ Cp, const float* __restrict__ bias,
                       int M, int N, int K, int lda, int ldb, int ldc) {
  __shared__ __align__(16) float As[16][68];
  __shared__ __align__(16) float Bs[16][68];
  const int tid = threadIdx.x;
  const int n0 = blockIdx.x * 64;
  const int m0 = blockIdx.y * 64;
  const int tx = tid & 15, ty = tid >> 4;
  const int arow = tid >> 2;
  const int acol = (tid & 3) * 4;
  float acc[4][4] = {};
  for (int k0 = 0; k0 < K; k0 += 16) {
    float4 a4 = *(const float4*)&A[(size_t)(m0 + arow) * lda + k0 + acol];
    As[acol + 0][arow] = a4.x; As[acol + 1][arow] = a4.y;
    As[acol + 2][arow] = a4.z; As[acol + 3][arow] = a4.w;
    if (BT) {
      float4 b4 = *(const float4*)&Bm[(size_t)(n0 + arow) * ldb + k0 + acol];
      Bs[acol + 0][arow] = b4.x; Bs[acol + 1][arow] = b4.y;
      Bs[acol + 2][arow] = b4.z; Bs[acol + 3][arow] = b4.w;
    } else {
      const int brow = tid >> 4;
      const int bcol = (tid & 15) * 4;
      float4 b4 = *(const float4*)&Bm[(size_t)(k0 + brow) * ldb + n0 + bcol];
      *(float4*)&Bs[brow][bcol] = b4;
    }
    __syncthreads();
#pragma unroll
    for (int kk = 0; kk < 16; kk++) {
      float4 av = *(const float4*)&As[kk][ty * 4];
      float4 bv = *(const float4*)&Bs[kk][tx * 4];
      float a_[4] = {av.x, av.y, av.z, av.w};
      float b_[4] = {bv.x, bv.y, bv.z, bv.w};
#pragma unroll
      for (int i = 0; i < 4; i++)
#pragma unroll
        for (int j = 0; j < 4; j++) acc[i][j] += a_[i] * b_[j];
    }
    __syncthreads();
  }
#pragma unroll
  for (int i = 0; i < 4; i++) {
    const int m = m0 + ty * 4 + i;
#pragma unroll
    for (int j = 0; j < 4; j++) {
      const int n = n0 + tx * 4 + j;
      float v = acc[i][j] + (bias ? bias[n] : 0.f);
      if (OBF) {
        if (CT) {
          int bb = m >> 9, sE = m & 511;
          ((bf16*)Cp)[((size_t)bb << 18) + (size_t)n * 512 + sE] = __float2bfloat16(v);
        } else {
          ((bf16*)Cp)[(size_t)m * ldc + n] = __float2bfloat16(v);
        }
      } else {
        ((float*)Cp)[(size_t)m * ldc + n] = v;
      }
    }
  }
}

// ---------------------------------------------------------------------------
// Small precompute kernels
// ---------------------------------------------------------------------------
__launch_bounds__(256)
__global__ void transpose512(const float* __restrict__ src, float* __restrict__ dst) {
  int idx = blockIdx.x * 256 + threadIdx.x;
  int r = idx >> 9, c = idx & 511;
  dst[(size_t)c * 512 + r] = src[idx];
}

__launch_bounds__(256)
__global__ void colvec_kernel(const float* __restrict__ bvec, const float* __restrict__ W,
                              float* __restrict__ outv) {
  int e = blockIdx.x * 256 + threadIdx.x;
  float acc = 0.f;
  for (int f = 0; f < 512; f++) acc += bvec[f] * W[(size_t)f * 512 + e];
  outv[e] = acc;
}

__launch_bounds__(256)
__global__ void dot_kernel(const float* __restrict__ a, const float* __restrict__ b,
                           float* __restrict__ outp) {
  __shared__ float red[256];
  int tid = threadIdx.x;
  red[tid] = a[tid] * b[tid] + a[tid + 256] * b[tid + 256];
  __syncthreads();
  for (int st = 128; st > 0; st >>= 1) {
    if (tid < st) red[tid] += red[tid + st];
    __syncthreads();
  }
  if (tid == 0) *outp = red[0];
}

__launch_bounds__(256)
__global__ void svec_kernel(const float* __restrict__ mem, const float* __restrict__ wb,
                            const float* __restrict__ dotc, float* __restrict__ svec) {
  __shared__ __align__(16) float ws_[512];
  int tid = threadIdx.x;
  *(float2*)&ws_[tid * 2] = *(const float2*)&wb[tid * 2];
  __syncthreads();
  int bs = blockIdx.x * 256 + tid;
  const float4* mr = (const float4*)&mem[(size_t)bs * 512];
  const float4* w4 = (const float4*)ws_;
  float acc = *dotc;
#pragma unroll 4
  for (int j = 0; j < 128; j++) {
    float4 m = mr[j], w = w4[j];
    acc += m.x * w.x + m.y * w.y + m.z * w.z + m.w * w.w;
  }
  svec[bs] = acc;
}

__launch_bounds__(256)
__global__ void biasg_kernel(const float* __restrict__ W_ih, const float* __restrict__ b_ih,
                             const float* __restrict__ b_hh, const float* __restrict__ bo,
                             float* __restrict__ biasg) {
  int j = blockIdx.x * 256 + threadIdx.x;
  float acc = b_ih[j] + b_hh[j];
  const float4* wr = (const float4*)&W_ih[(size_t)j * 640];
  const float4* br = (const float4*)bo;
#pragma unroll 4
  for (int f4 = 0; f4 < 128; f4++) {
    float4 w = wr[f4], bb = br[f4];
    acc += w.x * bb.x + w.y * bb.y + w.z * bb.z + w.w * bb.w;
  }
  biasg[j] = acc;
}

__launch_bounds__(256)
__global__ void wcomb_copy(const float* __restrict__ W_hh, const float* __restrict__ W_ih,
                           float* __restrict__ Wcomb) {
  int idx = blockIdx.x * 256 + threadIdx.x;
  int j = idx / 640, cc = idx % 640;
  float v = (cc < 512) ? W_hh[(size_t)j * 512 + cc] : W_ih[(size_t)j * 640 + cc];
  Wcomb[(size_t)j * 1152 + 512 + cc] = v;
}

// Wt[wq][k][nn] = Wcomb[wq*64+nn][k]  (per-slice contiguous)
__launch_bounds__(256)
__global__ void buildWt(const float* __restrict__ src, float* __restrict__ dst) {
  __shared__ float tile[32][33];
  const int n0 = blockIdx.x * 32, k0 = blockIdx.y * 32;   // grid (64, 36)
  const int x = threadIdx.x & 31, y0 = threadIdx.x >> 5;
  for (int y = y0; y < 32; y += 8)
    tile[y][x] = src[(size_t)(n0 + y) * 1152 + k0 + x];
  __syncthreads();
  const int wq = n0 >> 6, nb = n0 & 32;
  for (int y = y0; y < 32; y += 8)
    dst[(size_t)wq * 73728 + (size_t)(k0 + y) * 64 + nb + x] = tile[x][y];
}

// ---------------------------------------------------------------------------
// Persistent step-loop: 512 blocks x 512 threads, 2 blocks/CU (forced by
// __launch_bounds__(512,4): VGPR cap 128, 4 waves/SIMD -> all blocks resident).
// Attention role: b=blk&63, jj=blk>>6 (s-chunk of 64).
// Gates role: xcd=blk&7, blk2=blk>>3; wq=blk2&31 (n-slice 64), kh=blk2>>5
// (k-half 576). Wave w: k-sub [kh*576+w*72, +72); lane l: n column.
// ---------------------------------------------------------------------------
__launch_bounds__(512, 4)
__global__ void step_loop(const bf16* __restrict__ K2T, const bf16* __restrict__ Vv,
                          const float* __restrict__ svec, const float* __restrict__ Wt,
                          const float* __restrict__ biasg, const float* __restrict__ tgt,
                          const float* __restrict__ Wcls, const float* __restrict__ bcls,
                          float* __restrict__ ctxp, float* __restrict__ hx,
                          float* __restrict__ Gx, float* __restrict__ mlval,
                          unsigned* __restrict__ ctxcnt, unsigned* __restrict__ gatecnt,
                          float* __restrict__ out) {
  __shared__ __align__(16) float hs[512];
  __shared__ __align__(16) float abuf[4352];   // scores 64x68 | ctx 8x512 | gscr 8x8x64
  __shared__ __align__(16) float pbuf[64];
  __shared__ __align__(16) float Xs[8][576];   // this block's k-half of X, 8 batches

  const int blk = blockIdx.x, tid = threadIdx.x;
  const int b = blk & 63, jj = blk >> 6, s0 = jj * 64;
  const int xcd = blk & 7, blk2 = blk >> 3;
  const int wq = blk2 & 31, kh = blk2 >> 5;
  const float SCALE = 0.04419417382415922f;  // 1/sqrt(512)
  const int w = tid >> 6, l = tid & 63;
  const int eo = tid >> 3, so = tid & 7;

  // ---- W slice -> registers, once (72 fp32/thread) ----
  float wpk[72];
  {
    const float* wtb = Wt + (size_t)wq * 73728 + (size_t)(kh * 576 + w * 72) * 64 + l;
#pragma unroll
    for (int kk = 0; kk < 72; kk++) wpk[kk] = wtb[(size_t)kk * 64];
  }

  // ---- loop-invariant hoists ----
  const float bg0 = biasg[tid], bg1 = biasg[512 + tid],
              bg2 = biasg[1024 + tid], bg3 = biasg[1536 + tid];
  const int vl = tid >> 5, part = tid & 31, vout = jj * 16 + vl;
  const float bclsv = bcls[vout];
  const float svr = (tid < 64) ? svec[(size_t)b * 512 + s0 + tid] : 0.f;
  const uint4* kp = (const uint4*)&K2T[((size_t)b << 18) + (size_t)(eo * 8) * 512 + s0 + 8 * so];
  const uint4* vp = (const uint4*)&Vv[((size_t)b << 18) + (size_t)s0 * 512 + 8 * l];
  const float* gx0 = Gx + (size_t)b * 2048 + tid;
  const float* gx1 = gx0 + 131072;
  float creg = 0.f;

  for (int t = 0; t < 64; t++) {
    // ---- wait for step t-1 gates of this XCD (2 k-half layers), LSTM cell ----
    if (t > 0) {
      if (tid == 0)
        while (uld(&gatecnt[xcd]) < 64u * (unsigned)t) __builtin_amdgcn_s_sleep(1);
      __syncthreads();
      const float g0 = ald(gx0) + ald(gx1) + bg0;
      const float g1 = ald(gx0 + 512) + ald(gx1 + 512) + bg1;
      const float g2 = ald(gx0 + 1024) + ald(gx1 + 1024) + bg2;
      const float g3 = ald(gx0 + 1536) + ald(gx1 + 1536) + bg3;
      const float cn = sigm(g1) * creg + sigm(g0) * tanhf(g2);
      const float hn = sigm(g3) * tanhf(cn);
      creg = cn;
      hs[tid] = hn;
      if (jj < 4 && (tid >> 7) == jj) ast(&hx[((size_t)b << 9) + tid], hn);
    } else {
      hs[tid] = 0.f;
    }
    __syncthreads();

    // ---- attention scores: thread (eo,so) -> 8 s-elems, partial over 8 e ----
    {
      float a8[8] = {};
#pragma unroll 4
      for (int i = 0; i < 8; i++) {
        uint4 q = kp[(size_t)i * 64];
        float he = hs[eo * 8 + i];
        float2 p0 = bf2f2(q.x), p1 = bf2f2(q.y), p2 = bf2f2(q.z), p3 = bf2f2(q.w);
        a8[0] += he * p0.x; a8[1] += he * p0.y; a8[2] += he * p1.x; a8[3] += he * p1.y;
        a8[4] += he * p2.x; a8[5] += he * p2.y; a8[6] += he * p3.x; a8[7] += he * p3.y;
      }
      *(float4*)&abuf[eo * 68 + so * 8]     = make_float4(a8[0], a8[1], a8[2], a8[3]);
      *(float4*)&abuf[eo * 68 + so * 8 + 4] = make_float4(a8[4], a8[5], a8[6], a8[7]);
    }
    __syncthreads();
    // ---- single-wave softmax (wave 0 holds all 64 s) ----
    if (tid < 64) {
      float sv = 0.f;
#pragma unroll
      for (int eo2 = 0; eo2 < 64; eo2++) sv += abuf[eo2 * 68 + tid];
      const float pv = (sv + svr) * SCALE;
      float v = pv;
#pragma unroll
      for (int off = 32; off; off >>= 1) v = fmaxf(v, __shfl_down(v, off));
      const float mloc = __shfl(v, 0);
      const float ex = __expf(pv - mloc);
      pbuf[tid] = ex;
      float sm = ex;
#pragma unroll
      for (int off = 32; off; off >>= 1) sm += __shfl_down(sm, off);
      if (tid == 0) {
        ast(&mlval[(b * 8 + jj) * 2 + 0], mloc);
        ast(&mlval[(b * 8 + jj) * 2 + 1], sm);
      }
    }
    __syncthreads();
    // ---- ctx partial: wave w covers s = 8i+w; lane l owns 8 e's ----
    {
      float c8[8] = {};
#pragma unroll 4
      for (int i = 0; i < 8; i++) {
        const uint4 q = vp[(size_t)(i * 8 + w) * 64];
        const float ps = pbuf[i * 8 + w];
        float2 p0 = bf2f2(q.x), p1 = bf2f2(q.y), p2 = bf2f2(q.z), p3 = bf2f2(q.w);
        c8[0] += ps * p0.x; c8[1] += ps * p0.y; c8[2] += ps * p1.x; c8[3] += ps * p1.y;
        c8[4] += ps * p2.x; c8[5] += ps * p2.y; c8[6] += ps * p3.x; c8[7] += ps * p3.y;
      }
      const int k2 = (l >> 2) & 1, sw = k2 << 2;
      float4 lo = make_float4(c8[0], c8[1], c8[2], c8[3]);
      float4 hi = make_float4(c8[4], c8[5], c8[6], c8[7]);
      float4 first  = k2 ? hi : lo;
      float4 second = k2 ? lo : hi;
      const int base = w * 512 + 8 * l;
      *(float4*)&abuf[base + sw]     = first;
      *(float4*)&abuf[base + 4 - sw] = second;
    }
    __syncthreads();
    {
      float cx = 0.f;
#pragma unroll
      for (int w8 = 0; w8 < 8; w8++) cx += abuf[w8 * 512 + tid];
      ast(&ctxp[((size_t)(b * 8 + jj) << 9) + tid], cx);   // RAW partial post
    }
    __syncthreads();   // drain posts before the counter bump
    if (tid == 0)
      __hip_atomic_fetch_add(&ctxcnt[b], 1u, __ATOMIC_RELEASE, __HIP_MEMORY_SCOPE_AGENT);

    // ---- classifier for out[t-1] in the ctxcnt-wait window (off crit path) ----
    if (t > 0) {
      float a = 0.f;
#pragma unroll 2
      for (int q = 0; q < 4; q++) {
        const int qr = (q + part) & 3;
        float4 ww = *(const float4*)&Wcls[(size_t)vout * 512 + part * 16 + qr * 4];
        float4 hh = *(const float4*)&hs[part * 16 + qr * 4];
        a += ww.x * hh.x + ww.y * hh.y + ww.z * hh.z + ww.w * hh.w;
      }
      a += __shfl_xor(a, 1); a += __shfl_xor(a, 2);
      a += __shfl_xor(a, 4); a += __shfl_xor(a, 8); a += __shfl_xor(a, 16);
      if (part == 0) out[((size_t)b * 64 + (t - 1)) * 128 + vout] = a + bclsv;
    }

    // ---- wait for all 8 siblings of ALL 8 XCD batches ----
    if (tid < 8)
      while (uld(&ctxcnt[xcd + 8 * tid]) < 8u * (unsigned)(t + 1)) __builtin_amdgcn_s_sleep(1);
    __syncthreads();

    // ---- build Xs[8][576]: wave w assembles batch b2's k-half ----
    {
      const int b2 = xcd + 8 * w;
      const float* mlp = &mlval[b2 * 16];
      float mj[8], lj[8];
#pragma unroll
      for (int q2 = 0; q2 < 8; q2++) { mj[q2] = ald(mlp + 2 * q2); lj[q2] = ald(mlp + 2 * q2 + 1); }
      float M = mj[0];
#pragma unroll
      for (int q2 = 1; q2 < 8; q2++) M = fmaxf(M, mj[q2]);
      float L = 0.f;
#pragma unroll
      for (int q2 = 0; q2 < 8; q2++) L += __expf(mj[q2] - M) * lj[q2];
      float msc[8];
#pragma unroll
      for (int q2 = 0; q2 < 8; q2++) msc[q2] = __expf(mj[q2] - M) / L;
      const float* cp0 = &ctxp[(size_t)(b2 * 8) << 9];
      if (kh == 0) {
        // k 0..511: ctx (8-way combine); k 512..575: h[0..64)
#pragma unroll
        for (int e = 0; e < 512; e += 64) {
          const int ee = e + l;
          float x = 0.f;
#pragma unroll
          for (int q2 = 0; q2 < 8; q2++) x += msc[q2] * ald(cp0 + (q2 << 9) + ee);
          Xs[w][ee] = x;
        }
        Xs[w][512 + l] = ald(&hx[((size_t)b2 << 9) + l]);
      } else {
        // k 576..1023: h[64..512); k 1024..1151: tgt
#pragma unroll
        for (int c = 0; c < 7; c++)
          Xs[w][c * 64 + l] = ald(&hx[((size_t)b2 << 9) + 64 + c * 64 + l]);
#pragma unroll
        for (int c2 = 0; c2 < 2; c2++)
          Xs[w][448 + c2 * 64 + l] = tgt[((size_t)b2 * 64 + t) * 128 + c2 * 64 + l];
      }
    }
    __syncthreads();

    // ---- gates GEMM: reg-W x LDS-broadcast X, all 8 batches per thread ----
    {
      float acc[8] = {};
#pragma unroll
      for (int kk = 0; kk < 72; kk += 4) {
#pragma unroll
        for (int b8 = 0; b8 < 8; b8++) {
          const float4 xv = *(const float4*)&Xs[b8][w * 72 + kk];
          acc[b8] += xv.x * wpk[kk] + xv.y * wpk[kk + 1]
                   + xv.z * wpk[kk + 2] + xv.w * wpk[kk + 3];
        }
      }
#pragma unroll
      for (int b8 = 0; b8 < 8; b8++) abuf[(b8 * 8 + w) * 64 + l] = acc[b8];
    }
    __syncthreads();
    {
      const int b8 = tid >> 6, nn = tid & 63;
      float g = 0.f;
#pragma unroll
      for (int w8 = 0; w8 < 8; w8++) g += abuf[(b8 * 8 + w8) * 64 + nn];
      ast(&Gx[((size_t)kh << 17) + (size_t)(xcd + 8 * b8) * 2048 + wq * 64 + nn], g);
    }
    __syncthreads();   // drain gate posts
    if (tid == 0)
      __hip_atomic_fetch_add(&gatecnt[xcd], 1u, __ATOMIC_RELEASE, __HIP_MEMORY_SCOPE_AGENT);
  }

  // ---- epilogue: final cell (t=64) + classifier for out[63] ----
  if (tid == 0)
    while (uld(&gatecnt[xcd]) < 64u * 64u) __builtin_amdgcn_s_sleep(1);
  __syncthreads();
  {
    const float g0 = ald(gx0) + ald(gx1) + bg0;
    const float g1 = ald(gx0 + 512) + ald(gx1 + 512) + bg1;
    const float g2 = ald(gx0 + 1024) + ald(gx1 + 1024) + bg2;
    const float g3 = ald(gx0 + 1536) + ald(gx1 + 1536) + bg3;
    const float cn = sigm(g1) * creg + sigm(g0) * tanhf(g2);
    hs[tid] = sigm(g3) * tanhf(cn);
  }
  __syncthreads();
  {
    float a = 0.f;
#pragma unroll 2
    for (int q = 0; q < 4; q++) {
      const int qr = (q + part) & 3;
      float4 ww = *(const float4*)&Wcls[(size_t)vout * 512 + part * 16 + qr * 4];
      float4 hh = *(const float4*)&hs[part * 16 + qr * 4];
      a += ww.x * hh.x + ww.y * hh.y + ww.z * hh.z + ww.w * hh.w;
    }
    a += __shfl_xor(a, 1); a += __shfl_xor(a, 2);
    a += __shfl_xor(a, 4); a += __shfl_xor(a, 8); a += __shfl_xor(a, 16);
    if (part == 0) out[((size_t)b * 64 + 63) * 128 + vout] = a + bclsv;
  }
}

// ---------------------------------------------------------------------------
extern "C" void kernel_launch(void* const* d_in, const int* in_sizes, int n_in,
                              void* d_out, int out_size, void* d_ws, size_t ws_size,
                              hipStream_t stream) {
  const float* memory = (const float*)d_in[0];
  const float* tgt    = (const float*)d_in[1];
  const float* Wq     = (const float*)d_in[2];
  const float* bq     = (const float*)d_in[3];
  const float* Wk     = (const float*)d_in[4];
  const float* bk     = (const float*)d_in[5];
  const float* Wv     = (const float*)d_in[6];
  const float* bv     = (const float*)d_in[7];
  const float* Wo     = (const float*)d_in[8];
  const float* bo     = (const float*)d_in[9];
  const float* W_ih   = (const float*)d_in[10];
  const float* b_ih   = (const float*)d_in[11];
  const float* W_hh   = (const float*)d_in[12];
  const float* b_hh   = (const float*)d_in[13];
  const float* Wcls   = (const float*)d_in[14];
  const float* bcls   = (const float*)d_in[15];
  float* out = (float*)d_out;

  float* ws = (float*)d_ws;
  size_t off = 0;
  auto alloc = [&](size_t n) { size_t r = off; off += (n + 15) & ~(size_t)15; return r; };
  const size_t K2_off     = alloc(8388608);   // bf16 x 16777216: K2T [b][e][s]
  const size_t V_off      = alloc(8388608);   // bf16 x 16777216: V  [b][s][e]
  const size_t Wcomb_off  = alloc(2359296);   // 2048 x 1152 (n-major)
  const size_t Wt_off     = alloc(2359296);   // [wq=32][k=1152][nn=64]
  const size_t Wkq_off    = alloc(262144);
  const size_t WkT_off    = alloc(262144);
  const size_t svec_off   = alloc(32768);
  const size_t sb_off     = alloc(512);
  const size_t wb_off     = alloc(512);
  const size_t dotc_off   = alloc(16);
  const size_t biasg_off  = alloc(2048);
  const size_t hx_off     = alloc(32768);     // h posts [b][512]
  const size_t sync_off   = alloc(512);       // ctxcnt[64] @0, gatecnt[8] @64
  const size_t mlval_off  = alloc(1024);      // [b][jj=8][2]
  const size_t ctxp_off   = alloc(262144);    // raw ctx partials [b][jj=8][512]
  const size_t Gx_off     = alloc(262144);    // gates [kh=2][b][2048]

  bf16* K2T = (bf16*)(ws + K2_off);
  bf16* Vv  = (bf16*)(ws + V_off);
  unsigned* ctxcnt  = (unsigned*)(ws + sync_off);
  unsigned* gatecnt = ctxcnt + 64;

  // zero h posts and counters in one shot (adjacent allocs)
  hipMemsetAsync(ws + hx_off, 0, (32768 + 512) * sizeof(float), stream);

  // ---- precompute (step-invariant) ----
  transpose512<<<1024, 256, 0, stream>>>(Wk, ws + WkT_off);
  colvec_kernel<<<2, 256, 0, stream>>>(bk, Wq, ws + sb_off);
  colvec_kernel<<<2, 256, 0, stream>>>(bq, Wk, ws + wb_off);
  dot_kernel<<<1, 256, 0, stream>>>(bq, bk, ws + dotc_off);
  gemm64<false, false, false><<<dim3(8, 8), 256, 0, stream>>>(
      ws + WkT_off, Wq, ws + Wkq_off, nullptr, 512, 512, 512, 512, 512, 512);
  gemm64<false, true, true><<<dim3(8, 512), 256, 0, stream>>>(
      memory, ws + Wkq_off, K2T, ws + sb_off, 32768, 512, 512, 512, 512, 512);
  gemm64<true, true, false><<<dim3(8, 512), 256, 0, stream>>>(
      memory, Wv, Vv, bv, 32768, 512, 512, 512, 512, 512);
  gemm64<false, false, false><<<dim3(8, 32), 256, 0, stream>>>(
      W_ih, Wo, ws + Wcomb_off, nullptr, 2048, 512, 512, 640, 512, 1152);
  wcomb_copy<<<5120, 256, 0, stream>>>(W_hh, W_ih, ws + Wcomb_off);
  buildWt<<<dim3(64, 36), 256, 0, stream>>>(ws + Wcomb_off, ws + Wt_off);
  biasg_kernel<<<8, 256, 0, stream>>>(W_ih, b_ih, b_hh, bo, ws + biasg_off);
  svec_kernel<<<128, 256, 0, stream>>>(memory, ws + wb_off, ws + dotc_off, ws + svec_off);

  // ---- all 64 recurrent steps: 512 blocks, 2/CU, W in registers ----
  step_loop<<<512, 512, 0, stream>>>(K2T, Vv, ws + svec_off, ws + Wt_off,
                                     ws + biasg_off, tgt, Wcls, bcls,
                                     ws + ctxp_off, ws + hx_off, ws + Gx_off,
                                     ws + mlval_off, ctxcnt, gatecnt, out);
}

// Round 9
// 2554.164 us; speedup vs baseline: 2.1544x; 2.1544x over previous
//
#include <hip/hip_runtime.h>
#include <hip/hip_bf16.h>

// B=64, S=512, T=64, E=H=512, V=128, G=4H=2048, Kgates=512(ctx)+512(h)+128(tgt)=1152
// R10 = R6 + K pinned in LDS.
// R9 post-mortem: (512,4) cut VGPR budget to 64 -> wpk spilled (FETCH 4.76e6,
// R5 signature). Occupancy can't rise without killing W-in-regs. Instead kill
// the K stream: each block's K slice (128KB, t-invariant) lives in LDS
// permanently; V's 4MB/XCD working set then exactly fits L2. Gates Xs streamed
// in three 384-k thirds to fit the 160KB LDS budget (162312 B total).
// Config otherwise identical to R6 (best verified: 2690us, FETCH 2.55e6).

#define DI __device__ __forceinline__
typedef __hip_bfloat16 bf16;
typedef __hip_bfloat162 bf162;

DI float2 bf2f2(unsigned int u) {
  bf162 b = *reinterpret_cast<const bf162*>(&u);
  return __bfloat1622float2(b);
}
DI float sigm(float x) { return 1.f / (1.f + expf(-x)); }
DI void ast(float* p, float v) {
  __hip_atomic_store(p, v, __ATOMIC_RELAXED, __HIP_MEMORY_SCOPE_AGENT);
}
DI float ald(const float* p) {
  return __hip_atomic_load(p, __ATOMIC_RELAXED, __HIP_MEMORY_SCOPE_AGENT);
}
DI unsigned uld(const unsigned* p) {
  return __hip_atomic_load(p, __ATOMIC_RELAXED, __HIP_MEMORY_SCOPE_AGENT);
}

// ---------------------------------------------------------------------------
// Generic 64x64-tile fp32 GEMM (precompute only, unchanged)
// ---------------------------------------------------------------------------
template<bool BT, bool OBF, bool CT>
__launch_bounds__(256)
__global__ void gemm64(const float* __restrict__ A, const float* __restrict__ Bm,
                       void* __restrict__ Cp, const float* __restrict__ bias,
                       int M, int N, int K, int lda, int ldb, int ldc) {
  __shared__ __align__(16) float As[16][68];
  __shared__ __align__(16) float Bs[16][68];
  const int tid = threadIdx.x;
  const int n0 = blockIdx.x * 64;
  const int m0 = blockIdx.y * 64;
  const int tx = tid & 15, ty = tid >> 4;
  const int arow = tid >> 2;
  const int acol = (tid & 3) * 4;
  float acc[4][4] = {};
  for (int k0 = 0; k0 < K; k0 += 16) {
    float4 a4 = *(const float4*)&A[(size_t)(m0 + arow) * lda + k0 + acol];
    As[acol + 0][arow] = a4.x; As[acol + 1][arow] = a4.y;
    As[acol + 2][arow] = a4.z; As[acol + 3][arow] = a4.w;
    if (BT) {
      float4 b4 = *(const float4*)&Bm[(size_t)(n0 + arow) * ldb + k0 + acol];
      Bs[acol + 0][arow] = b4.x; Bs[acol + 1][arow] = b4.y;
      Bs[acol + 2][arow] = b4.z; Bs[acol + 3][arow] = b4.w;
    } else {
      const int brow = tid >> 4;
      const int bcol = (tid & 15) * 4;
      float4 b4 = *(const float4*)&Bm[(size_t)(k0 + brow) * ldb + n0 + bcol];
      *(float4*)&Bs[brow][bcol] = b4;
    }
    __syncthreads();
#pragma unroll
    for (int kk = 0; kk < 16; kk++) {
      float4 av = *(const float4*)&As[kk][ty * 4];
      float4 bv = *(const float4*)&Bs[kk][tx * 4];
      float a_[4] = {av.x, av.y, av.z, av.w};
      float b_[4] = {bv.x, bv.y, bv.z, bv.w};
#pragma unroll
      for (int i = 0; i < 4; i++)
#pragma unroll
        for (int j = 0; j < 4; j++) acc[i][j] += a_[i] * b_[j];
    }
    __syncthreads();
  }
#pragma unroll
  for (int i = 0; i < 4; i++) {
    const int m = m0 + ty * 4 + i;
#pragma unroll
    for (int j = 0; j < 4; j++) {
      const int n = n0 + tx * 4 + j;
      float v = acc[i][j] + (bias ? bias[n] : 0.f);
      if (OBF) {
        if (CT) {
          int bb = m >> 9, sE = m & 511;
          ((bf16*)Cp)[((size_t)bb << 18) + (size_t)n * 512 + sE] = __float2bfloat16(v);
        } else {
          ((bf16*)Cp)[(size_t)m * ldc + n] = __float2bfloat16(v);
        }
      } else {
        ((float*)Cp)[(size_t)m * ldc + n] = v;
      }
    }
  }
}

// ---------------------------------------------------------------------------
// Small precompute kernels
// ---------------------------------------------------------------------------
__launch_bounds__(256)
__global__ void transpose512(const float* __restrict__ src, float* __restrict__ dst) {
  int idx = blockIdx.x * 256 + threadIdx.x;
  int r = idx >> 9, c = idx & 511;
  dst[(size_t)c * 512 + r] = src[idx];
}

__launch_bounds__(256)
__global__ void colvec_kernel(const float* __restrict__ bvec, const float* __restrict__ W,
                              float* __restrict__ outv) {
  int e = blockIdx.x * 256 + threadIdx.x;
  float acc = 0.f;
  for (int f = 0; f < 512; f++) acc += bvec[f] * W[(size_t)f * 512 + e];
  outv[e] = acc;
}

__launch_bounds__(256)
__global__ void dot_kernel(const float* __restrict__ a, const float* __restrict__ b,
                           float* __restrict__ outp) {
  __shared__ float red[256];
  int tid = threadIdx.x;
  red[tid] = a[tid] * b[tid] + a[tid + 256] * b[tid + 256];
  __syncthreads();
  for (int st = 128; st > 0; st >>= 1) {
    if (tid < st) red[tid] += red[tid + st];
    __syncthreads();
  }
  if (tid == 0) *outp = red[0];
}

__launch_bounds__(256)
__global__ void svec_kernel(const float* __restrict__ mem, const float* __restrict__ wb,
                            const float* __restrict__ dotc, float* __restrict__ svec) {
  __shared__ __align__(16) float ws_[512];
  int tid = threadIdx.x;
  *(float2*)&ws_[tid * 2] = *(const float2*)&wb[tid * 2];
  __syncthreads();
  int bs = blockIdx.x * 256 + tid;
  const float4* mr = (const float4*)&mem[(size_t)bs * 512];
  const float4* w4 = (const float4*)ws_;
  float acc = *dotc;
#pragma unroll 4
  for (int j = 0; j < 128; j++) {
    float4 m = mr[j], w = w4[j];
    acc += m.x * w.x + m.y * w.y + m.z * w.z + m.w * w.w;
  }
  svec[bs] = acc;
}

__launch_bounds__(256)
__global__ void biasg_kernel(const float* __restrict__ W_ih, const float* __restrict__ b_ih,
                             const float* __restrict__ b_hh, const float* __restrict__ bo,
                             float* __restrict__ biasg) {
  int j = blockIdx.x * 256 + threadIdx.x;
  float acc = b_ih[j] + b_hh[j];
  const float4* wr = (const float4*)&W_ih[(size_t)j * 640];
  const float4* br = (const float4*)bo;
#pragma unroll 4
  for (int f4 = 0; f4 < 128; f4++) {
    float4 w = wr[f4], bb = br[f4];
    acc += w.x * bb.x + w.y * bb.y + w.z * bb.z + w.w * bb.w;
  }
  biasg[j] = acc;
}

__launch_bounds__(256)
__global__ void wcomb_copy(const float* __restrict__ W_hh, const float* __restrict__ W_ih,
                           float* __restrict__ Wcomb) {
  int idx = blockIdx.x * 256 + threadIdx.x;
  int j = idx / 640, cc = idx % 640;
  float v = (cc < 512) ? W_hh[(size_t)j * 512 + cc] : W_ih[(size_t)j * 640 + cc];
  Wcomb[(size_t)j * 1152 + 512 + cc] = v;
}

// Wt[wq][k][nn] = Wcomb[wq*64+nn][k]  (per-slice contiguous)
__launch_bounds__(256)
__global__ void buildWt(const float* __restrict__ src, float* __restrict__ dst) {
  __shared__ float tile[32][33];
  const int n0 = blockIdx.x * 32, k0 = blockIdx.y * 32;   // grid (64, 36)
  const int x = threadIdx.x & 31, y0 = threadIdx.x >> 5;
  for (int y = y0; y < 32; y += 8)
    tile[y][x] = src[(size_t)(n0 + y) * 1152 + k0 + x];
  __syncthreads();
  const int wq = n0 >> 6, nb = n0 & 32;
  for (int y = y0; y < 32; y += 8)
    dst[(size_t)wq * 73728 + (size_t)(k0 + y) * 64 + nb + x] = tile[x][y];
}

// ---------------------------------------------------------------------------
// Persistent step-loop: 256 blocks x 512 threads, no grid barriers.
// W in VGPRs (R6-proven), K slice pinned in LDS (new).
// Attention role: b=blk&63, jj=blk>>6 (s-chunk 128). Gates role: xcd=blk&7,
// wq=blk>>3; wave w covers k = {p*384 + w*48 + j} over 3 Xs passes.
// ---------------------------------------------------------------------------
__launch_bounds__(512, 1)
__global__ void step_loop(const bf16* __restrict__ K2T, const bf16* __restrict__ Vv,
                          const float* __restrict__ svec, const float* __restrict__ Wt,
                          const float* __restrict__ biasg, const float* __restrict__ tgt,
                          const float* __restrict__ Wcls, const float* __restrict__ bcls,
                          float* __restrict__ ctxp, float* __restrict__ hx,
                          float* __restrict__ Gx, float* __restrict__ mlval,
                          unsigned* __restrict__ ctxcnt, unsigned* __restrict__ gatecnt,
                          float* __restrict__ out) {
  __shared__ __align__(16) bf16 Klds[512][128];   // 128 KB: this block's K slice
  __shared__ __align__(16) float abuf[4096];      // scores 8x128 | ctx 8x512 | gscr 8x8x64
  __shared__ __align__(16) float Xs[8][384];      // gates X third (12.3 KB)
  __shared__ __align__(16) float hs[512];
  __shared__ __align__(16) float pbuf[128];
  __shared__ float red2[2];

  const int blk = blockIdx.x, tid = threadIdx.x;
  const int b = blk & 63, jj = blk >> 6, s0 = jj * 128;
  const int xcd = blk & 7, wq = blk >> 3;
  const float SCALE = 0.04419417382415922f;  // 1/sqrt(512)
  const int w = tid >> 6, l = tid & 63;

  // ---- K slice -> LDS, once (t-invariant addresses) ----
  {
    const uint4* kg = (const uint4*)&K2T[((size_t)b << 18) + s0];  // row stride 64 uint4
    uint4* kl = (uint4*)&Klds[0][0];
    for (int idx = tid; idx < 8192; idx += 512) {
      const int e = idx >> 4, q = idx & 15;
      kl[idx] = kg[(size_t)e * 64 + q];
    }
  }

  // ---- W slice -> registers, once (144 fp32/thread; pass-major k order) ----
  float wpk[144];
  {
    const float* wtb = Wt + (size_t)wq * 73728 + l;
#pragma unroll
    for (int p = 0; p < 3; p++)
#pragma unroll
      for (int j = 0; j < 48; j++)
        wpk[p * 48 + j] = wtb[(size_t)(p * 384 + w * 48 + j) * 64];
  }

  // ---- loop-invariant hoists ----
  const float bg0 = biasg[tid], bg1 = biasg[512 + tid],
              bg2 = biasg[1024 + tid], bg3 = biasg[1536 + tid];
  const int vl = tid >> 4, part = tid & 15, vout = jj * 32 + vl;
  const float bclsv = bcls[vout];
  const float svr = (tid < 128) ? svec[(size_t)b * 512 + s0 + tid] : 0.f;
  const uint4* vp = (const uint4*)&Vv[((size_t)b << 18) + (size_t)s0 * 512 + 8 * l];
  const float* gx0 = Gx + (size_t)b * 2048 + tid;
  float creg = 0.f;
  __syncthreads();   // Klds ready

  for (int t = 0; t < 64; t++) {
    // ---- wait for step t-1 gates of this XCD, then LSTM cell ----
    if (t > 0) {
      if (tid == 0)
        while (uld(&gatecnt[xcd]) < 32u * (unsigned)t) __builtin_amdgcn_s_sleep(1);
      __syncthreads();
      const float g0 = ald(gx0) + bg0;
      const float g1 = ald(gx0 + 512) + bg1;
      const float g2 = ald(gx0 + 1024) + bg2;
      const float g3 = ald(gx0 + 1536) + bg3;
      const float cn = sigm(g1) * creg + sigm(g0) * tanhf(g2);
      const float hn = sigm(g3) * tanhf(cn);
      creg = cn;
      hs[tid] = hn;
      if ((tid >> 7) == jj) ast(&hx[((size_t)b << 9) + tid], hn);  // quarter post
    } else {
      hs[tid] = 0.f;
    }
    __syncthreads();

    // ---- attention scores from LDS K: wave w covers e [w*64,+64), lane=2 s ----
    {
      float p0 = 0.f, p1 = 0.f;
      const unsigned* kr = (const unsigned*)&Klds[w * 64][0] + l;   // +64 dwords per e
#pragma unroll 8
      for (int i = 0; i < 64; i++) {
        const float2 kf = bf2f2(kr[i * 64]);
        const float he = hs[w * 64 + i];
        p0 += he * kf.x; p1 += he * kf.y;
      }
      abuf[w * 128 + 2 * l]     = p0;
      abuf[w * 128 + 2 * l + 1] = p1;
    }
    __syncthreads();
    float pv = 0.f;
    if (tid < 128) {
      float sv = 0.f;
#pragma unroll
      for (int w8 = 0; w8 < 8; w8++) sv += abuf[w8 * 128 + tid];
      pv = (sv + svr) * SCALE;
      pbuf[tid] = pv;
    }
    __syncthreads();
    if (tid < 64) {
      float v = fmaxf(pbuf[tid], pbuf[tid + 64]);
#pragma unroll
      for (int off = 32; off; off >>= 1) v = fmaxf(v, __shfl_down(v, off));
      if (tid == 0) red2[0] = v;
    }
    __syncthreads();
    const float mloc = red2[0];
    if (tid < 128) pbuf[tid] = __expf(pv - mloc);
    __syncthreads();
    if (tid < 64) {
      float v = pbuf[tid] + pbuf[tid + 64];
#pragma unroll
      for (int off = 32; off; off >>= 1) v += __shfl_down(v, off);
      if (tid == 0) red2[1] = v;
    }
    __syncthreads();
    if (tid == 0) {
      ast(&mlval[(b * 4 + jj) * 2 + 0], mloc);
      ast(&mlval[(b * 4 + jj) * 2 + 1], red2[1]);
    }
    // ---- ctx partial (V from global/L2): wave w covers s = 8i+w ----
    {
      float c8[8] = {};
#pragma unroll 8
      for (int i = 0; i < 16; i++) {
        const uint4 q = vp[(size_t)(i * 8 + w) * 64];
        const float ps = pbuf[i * 8 + w];
        float2 p0 = bf2f2(q.x), p1 = bf2f2(q.y), p2 = bf2f2(q.z), p3 = bf2f2(q.w);
        c8[0] += ps * p0.x; c8[1] += ps * p0.y; c8[2] += ps * p1.x; c8[3] += ps * p1.y;
        c8[4] += ps * p2.x; c8[5] += ps * p2.y; c8[6] += ps * p3.x; c8[7] += ps * p3.y;
      }
      const int k2 = (l >> 2) & 1, sw = k2 << 2;
      float4 lo = make_float4(c8[0], c8[1], c8[2], c8[3]);
      float4 hi = make_float4(c8[4], c8[5], c8[6], c8[7]);
      float4 first  = k2 ? hi : lo;
      float4 second = k2 ? lo : hi;
      const int base = w * 512 + 8 * l;
      *(float4*)&abuf[base + sw]     = first;
      *(float4*)&abuf[base + 4 - sw] = second;
    }
    __syncthreads();
    {
      float cx = 0.f;
#pragma unroll
      for (int w8 = 0; w8 < 8; w8++) cx += abuf[w8 * 512 + tid];
      ast(&ctxp[((size_t)(b * 4 + jj) << 9) + tid], cx);   // RAW partial post
    }
    __syncthreads();   // drain posts before the counter bump
    if (tid == 0)
      __hip_atomic_fetch_add(&ctxcnt[b], 1u, __ATOMIC_RELAXED, __HIP_MEMORY_SCOPE_AGENT);

    // ---- classifier for out[t-1] in the ctxcnt-wait window (off crit path) ----
    if (t > 0) {
      float a = 0.f;
#pragma unroll
      for (int q = 0; q < 8; q++) {
        const int qr = (q + part) & 7;
        float4 ww = *(const float4*)&Wcls[(size_t)vout * 512 + part * 32 + qr * 4];
        float4 hh = *(const float4*)&hs[part * 32 + qr * 4];
        a += ww.x * hh.x + ww.y * hh.y + ww.z * hh.z + ww.w * hh.w;
      }
      a += __shfl_xor(a, 1); a += __shfl_xor(a, 2);
      a += __shfl_xor(a, 4); a += __shfl_xor(a, 8);
      if (part == 0) out[((size_t)b * 64 + (t - 1)) * 128 + vout] = a + bclsv;
    }

    // ---- wait for all 4 siblings of ALL 8 XCD batches ----
    if (tid < 8)
      while (uld(&ctxcnt[xcd + 8 * tid]) < 4u * (unsigned)(t + 1)) __builtin_amdgcn_s_sleep(1);
    __syncthreads();

    // ---- gates: 3 passes of {build Xs third, FMA} — wave w owns batch b2 ----
    {
      const int b2 = xcd + 8 * w;
      float msc4[4];
      {
        const float* mlp = &mlval[b2 * 8];
        float mj[4], lj[4];
#pragma unroll
        for (int q2 = 0; q2 < 4; q2++) { mj[q2] = ald(mlp + 2 * q2); lj[q2] = ald(mlp + 2 * q2 + 1); }
        const float M = fmaxf(fmaxf(mj[0], mj[1]), fmaxf(mj[2], mj[3]));
        const float L = __expf(mj[0] - M) * lj[0] + __expf(mj[1] - M) * lj[1]
                      + __expf(mj[2] - M) * lj[2] + __expf(mj[3] - M) * lj[3];
#pragma unroll
        for (int q2 = 0; q2 < 4; q2++) msc4[q2] = __expf(mj[q2] - M) / L;
      }
      const float* cp0 = &ctxp[(size_t)(b2 * 4) << 9];
      float acc[8] = {};
#pragma unroll 1
      for (int p = 0; p < 3; p++) {
#pragma unroll
        for (int c = 0; c < 6; c++) {
          const int k = p * 384 + c * 64 + l;
          float x;
          if (k < 512) {
            x = msc4[0] * ald(cp0 + k)        + msc4[1] * ald(cp0 + 512 + k)
              + msc4[2] * ald(cp0 + 1024 + k) + msc4[3] * ald(cp0 + 1536 + k);
          } else if (k < 1024) {
            x = ald(&hx[((size_t)b2 << 9) + (k - 512)]);
          } else {
            x = tgt[((size_t)b2 * 64 + t) * 128 + (k - 1024)];
          }
          Xs[w][c * 64 + l] = x;
        }
        __syncthreads();
#pragma unroll
        for (int kk = 0; kk < 48; kk += 4) {
#pragma unroll
          for (int b8 = 0; b8 < 8; b8++) {
            const float4 xv = *(const float4*)&Xs[b8][w * 48 + kk];
            acc[b8] += xv.x * wpk[p * 48 + kk]     + xv.y * wpk[p * 48 + kk + 1]
                     + xv.z * wpk[p * 48 + kk + 2] + xv.w * wpk[p * 48 + kk + 3];
          }
        }
        __syncthreads();
      }
      // cross-wave reduce via LDS scratch (abuf reuse)
#pragma unroll
      for (int b8 = 0; b8 < 8; b8++) abuf[(b8 * 8 + w) * 64 + l] = acc[b8];
    }
    __syncthreads();
    {
      const int b8 = tid >> 6, nn = tid & 63;
      float g = 0.f;
#pragma unroll
      for (int w8 = 0; w8 < 8; w8++) g += abuf[(b8 * 8 + w8) * 64 + nn];
      ast(&Gx[(size_t)(xcd + 8 * b8) * 2048 + wq * 64 + nn], g);
    }
    __syncthreads();   // drain gate posts
    if (tid == 0)
      __hip_atomic_fetch_add(&gatecnt[xcd], 1u, __ATOMIC_RELAXED, __HIP_MEMORY_SCOPE_AGENT);
  }

  // ---- epilogue: final cell (t=64) + classifier for out[63] ----
  if (tid == 0)
    while (uld(&gatecnt[xcd]) < 32u * 64u) __builtin_amdgcn_s_sleep(1);
  __syncthreads();
  {
    const float g0 = ald(gx0) + bg0;
    const float g1 = ald(gx0 + 512) + bg1;
    const float g2 = ald(gx0 + 1024) + bg2;
    const float g3 = ald(gx0 + 1536) + bg3;
    const float cn = sigm(g1) * creg + sigm(g0) * tanhf(g2);
    hs[tid] = sigm(g3) * tanhf(cn);
  }
  __syncthreads();
  {
    float a = 0.f;
#pragma unroll
    for (int q = 0; q < 8; q++) {
      const int qr = (q + part) & 7;
      float4 ww = *(const float4*)&Wcls[(size_t)vout * 512 + part * 32 + qr * 4];
      float4 hh = *(const float4*)&hs[part * 32 + qr * 4];
      a += ww.x * hh.x + ww.y * hh.y + ww.z * hh.z + ww.w * hh.w;
    }
    a += __shfl_xor(a, 1); a += __shfl_xor(a, 2);
    a += __shfl_xor(a, 4); a += __shfl_xor(a, 8);
    if (part == 0) out[((size_t)b * 64 + 63) * 128 + vout] = a + bclsv;
  }
}

// ---------------------------------------------------------------------------
extern "C" void kernel_launch(void* const* d_in, const int* in_sizes, int n_in,
                              void* d_out, int out_size, void* d_ws, size_t ws_size,
                              hipStream_t stream) {
  const float* memory = (const float*)d_in[0];
  const float* tgt    = (const float*)d_in[1];
  const float* Wq     = (const float*)d_in[2];
  const float* bq     = (const float*)d_in[3];
  const float* Wk     = (const float*)d_in[4];
  const float* bk     = (const float*)d_in[5];
  const float* Wv     = (const float*)d_in[6];
  const float* bv     = (const float*)d_in[7];
  const float* Wo     = (const float*)d_in[8];
  const float* bo     = (const float*)d_in[9];
  const float* W_ih   = (const float*)d_in[10];
  const float* b_ih   = (const float*)d_in[11];
  const float* W_hh   = (const float*)d_in[12];
  const float* b_hh   = (const float*)d_in[13];
  const float* Wcls   = (const float*)d_in[14];
  const float* bcls   = (const float*)d_in[15];
  float* out = (float*)d_out;

  float* ws = (float*)d_ws;
  size_t off = 0;
  auto alloc = [&](size_t n) { size_t r = off; off += (n + 15) & ~(size_t)15; return r; };
  const size_t K2_off     = alloc(8388608);   // bf16 x 16777216: K2T [b][e][s]
  const size_t V_off      = alloc(8388608);   // bf16 x 16777216: V  [b][s][e]
  const size_t Wcomb_off  = alloc(2359296);   // 2048 x 1152 (n-major)
  const size_t Wt_off     = alloc(2359296);   // [wq=32][k=1152][nn=64]
  const size_t Wkq_off    = alloc(262144);
  const size_t WkT_off    = alloc(262144);
  const size_t svec_off   = alloc(32768);
  const size_t sb_off     = alloc(512);
  const size_t wb_off     = alloc(512);
  const size_t dotc_off   = alloc(16);
  const size_t biasg_off  = alloc(2048);
  const size_t hx_off     = alloc(32768);     // h posts [b][512]
  const size_t sync_off   = alloc(512);       // ctxcnt[64] @0, gatecnt[8] @64
  const size_t mlval_off  = alloc(512);       // [b][jj][2]
  const size_t ctxp_off   = alloc(131072);    // raw ctx partials [b][jj][512]
  const size_t Gx_off     = alloc(131072);    // gates [b][2048]

  bf16* K2T = (bf16*)(ws + K2_off);
  bf16* Vv  = (bf16*)(ws + V_off);
  unsigned* ctxcnt  = (unsigned*)(ws + sync_off);
  unsigned* gatecnt = ctxcnt + 64;

  // zero h posts and counters in one shot (adjacent allocs)
  hipMemsetAsync(ws + hx_off, 0, (32768 + 512) * sizeof(float), stream);

  // ---- precompute (step-invariant) ----
  transpose512<<<1024, 256, 0, stream>>>(Wk, ws + WkT_off);
  colvec_kernel<<<2, 256, 0, stream>>>(bk, Wq, ws + sb_off);
  colvec_kernel<<<2, 256, 0, stream>>>(bq, Wk, ws + wb_off);
  dot_kernel<<<1, 256, 0, stream>>>(bq, bk, ws + dotc_off);
  gemm64<false, false, false><<<dim3(8, 8), 256, 0, stream>>>(
      ws + WkT_off, Wq, ws + Wkq_off, nullptr, 512, 512, 512, 512, 512, 512);
  gemm64<false, true, true><<<dim3(8, 512), 256, 0, stream>>>(
      memory, ws + Wkq_off, K2T, ws + sb_off, 32768, 512, 512, 512, 512, 512);
  gemm64<true, true, false><<<dim3(8, 512), 256, 0, stream>>>(
      memory, Wv, Vv, bv, 32768, 512, 512, 512, 512, 512);
  gemm64<false, false, false><<<dim3(8, 32), 256, 0, stream>>>(
      W_ih, Wo, ws + Wcomb_off, nullptr, 2048, 512, 512, 640, 512, 1152);
  wcomb_copy<<<5120, 256, 0, stream>>>(W_hh, W_ih, ws + Wcomb_off);
  buildWt<<<dim3(64, 36), 256, 0, stream>>>(ws + Wcomb_off, ws + Wt_off);
  biasg_kernel<<<8, 256, 0, stream>>>(W_ih, b_ih, b_hh, bo, ws + biasg_off);
  svec_kernel<<<128, 256, 0, stream>>>(memory, ws + wb_off, ws + dotc_off, ws + svec_off);

  // ---- all 64 recurrent steps: K in LDS, W in registers ----
  step_loop<<<256, 512, 0, stream>>>(K2T, Vv, ws + svec_off, ws + Wt_off,
                                     ws + biasg_off, tgt, Wcls, bcls,
                                     ws + ctxp_off, ws + hx_off, ws + Gx_off,
                                     ws + mlval_off, ctxcnt, gatecnt, out);
}